// Round 20
// baseline (177.835 us; speedup 1.0000x reference)
//
#include <hip/hip_runtime.h>

// GRU decoder via MFMA, round 15: B=32768, T=48, F=16, H=32.
// = R14 (verified 58.6us, absmax 0.0078125) + DEFERRED DENSE REDUCE + lean
// B-frag masking. Insight: R13 removed the po FEEDBACK but kept swz16+bperm
// IN the loop; lgkm ops consumed immediately -> ~120cy exposed LDS-pipe
// latency per step in program order (why R13 == R11). Fix:
//  (1) In-loop dense = 8 fma + ds_write of per-lane partial (no wait, no
//      consumer until epilogue). Epilogue sums 4 quad-partials per (t,row)
//      pairwise (q0+q1)+(q2+q3)+dbs -- bit-identical to the old swz/bperm
//      tree -- and stores coalesced.
//  (2) zm masking removed: B slots 18-31 hit ZERO A-weights, garbage is
//      harmless; only quad2 u[0] (K=16/17 = w0 rows) needs control -> one
//      AND with precomputed mask. Step 0 (delta injection) peeled.
// State recurrence math unchanged from R13/R14 (verified): rank-1 po-fold,
// permuted gate-column m-order hid(r,T)=(r>>2)*8+T*4+(r&3) -> D-output ==
// next-step B-frag (lane-local, no LDS/barrier/cross-lane in chain),
// stage-wise 5-trans gates, 14 MFMAs/step.
// Grid 2048 x 64thr (1-wave blocks, 2 waves/SIMD). obuf 48x64 f32 = 12KB.
// Layouts (verified m89/m91/m120):
//   D[m][n]: col=lane&15=batch, row=(lane>>4)*4+reg  (m = PERMUTED gatecol)
//   A[m=lane&15][k=(lane>>4)*8+j] ; B[k=(lane>>4)*8+j][n=lane&15]

typedef __attribute__((ext_vector_type(8))) short short8;
typedef __attribute__((ext_vector_type(4))) float f32x4;

constexpr int T_STEPS  = 48;
constexpr int F_DIM    = 16;
constexpr int H_DIM    = 32;

union S8 { short8 s; unsigned u[4]; };

__device__ __forceinline__ unsigned pk_bf16(float hi, float lo) {
    // (bf16(hi)<<16)|bf16(lo), round-half-up
    return __builtin_amdgcn_perm(__float_as_uint(hi) + 0x8000u,
                                 __float_as_uint(lo) + 0x8000u, 0x07060302u);
}
__device__ __forceinline__ short bf16s(float x) {
    return (short)((__float_as_uint(x) + 0x8000u) >> 16);
}
__device__ __forceinline__ float rcpf(float x) { return __builtin_amdgcn_rcpf(x); }
__device__ __forceinline__ float ex2(float x)  { return __builtin_amdgcn_exp2f(x); }
#define MFMA(a, b, c) __builtin_amdgcn_mfma_f32_16x16x32_bf16(a, b, c, 0, 0, 0)
#define SWZ16(v) __int_as_float(__builtin_amdgcn_ds_swizzle(__float_as_int(v), 0x401F))
#define BPERM(a, v) __builtin_amdgcn_ds_bpermute((a), (v))

__global__ __launch_bounds__(64, 2)
void gru_mfma15(const float* __restrict__ feat,     // [B,T,F]
                const float* __restrict__ init_in,  // [B,1]
                const float* __restrict__ init_h,   // [B,H]
                const float* __restrict__ Wk,       // [17,96]
                const float* __restrict__ Rk,       // [32,96]
                const float* __restrict__ bx,       // [96]
                const float* __restrict__ bh,       // [96]
                const float* __restrict__ dw,       // [32]
                const float* __restrict__ db,       // [1]
                float* __restrict__ out)            // [B,T]
{
    __shared__ __align__(16) float obuf[T_STEPS * 64];   // per-lane dense partials

    const int lane = threadIdx.x;             // block = 64 = ONE wave
    const int ln   = lane & 15;               // batch col
    const int quad = lane >> 4;
    const int b0   = blockIdx.x * 16;
    const int bpa  = (lane ^ 32) << 2;        // xor32 bpermute addr (prologue only)

    const float SZ = -1.44269504088896340736f;   // -log2(e)  (sigmoid args)
    const float SC =  2.88539008177792681472f;   // 2*log2(e) (tanh arg)

    // Permuted A-column for this lane's m-row (ln): cA(T) = (ln>>2)*8+T*4+(ln&3)
    const int cA0 = (ln >> 2) * 8 + (ln & 3);
    const int cA1 = cA0 + 4;

    // ---- A-operand weight fragments (R13 layout, verified) ----
    S8 WzA, WrA, WhA, WzB, WrB, WhB, RzA, RrA, RhA, RzB, RrB, RhB, DwhA, DwhB;
#pragma unroll
    for (int j = 0; j < 8; ++j) {
        const int k = quad * 8 + j;
        float wzA = 0, wrA = 0, whA = 0, wzB = 0, wrB = 0, whB = 0;
        if (k < 16) {                       // feat rows 0..15 -> Wk rows 1..16
            const float* Wrow = Wk + (size_t)(k + 1) * 96;
            wzA = Wrow[cA0]; wrA = Wrow[32 + cA0]; whA = Wrow[64 + cA0];
            wzB = Wrow[cA1]; wrB = Wrow[32 + cA1]; whB = Wrow[64 + cA1];
        } else if (k < 18) {                // k=16: delta_hi, k=17: delta_lo
            wzA = Wk[cA0]; wrA = Wk[32 + cA0]; whA = Wk[64 + cA0];
            wzB = Wk[cA1]; wrB = Wk[32 + cA1]; whB = Wk[64 + cA1];
        }
        WzA.s[j] = bf16s(SZ * wzA); WrA.s[j] = bf16s(SZ * wrA); WhA.s[j] = bf16s(SC * whA);
        WzB.s[j] = bf16s(SZ * wzB); WrB.s[j] = bf16s(SZ * wrB); WhB.s[j] = bf16s(SC * whB);
        const float* Rrow = Rk + (size_t)k * 96;
        const float dwk = dw[k];
        RzA.s[j]  = bf16s(SZ * (Rrow[cA0]      + dwk * Wk[cA0]));
        RrA.s[j]  = bf16s(SZ * (Rrow[32 + cA0] + dwk * Wk[32 + cA0]));
        RhA.s[j]  = bf16s(SC * Rrow[64 + cA0]);
        DwhA.s[j] = bf16s(SC * dwk * Wk[64 + cA0]);
        RzB.s[j]  = bf16s(SZ * (Rrow[cA1]      + dwk * Wk[cA1]));
        RrB.s[j]  = bf16s(SZ * (Rrow[32 + cA1] + dwk * Wk[32 + cA1]));
        RhB.s[j]  = bf16s(SC * Rrow[64 + cA1]);
        DwhB.s[j] = bf16s(SC * dwk * Wk[64 + cA1]);
    }

    // ---- per-lane D-side constants: c = quad*8 + T*4 + i (R13, verified) ----
    const float dbs = db[0];
    f32x4 czA, crA, chA, cgA, czB, crB, chB, cgB, dwA, dwB;
#pragma unroll
    for (int i = 0; i < 4; ++i) {
        const int c0 = quad * 8 + i, c1 = c0 + 4;
        czA[i] = SZ * (bx[c0] + bh[c0] + dbs * Wk[c0]);
        czB[i] = SZ * (bx[c1] + bh[c1] + dbs * Wk[c1]);
        crA[i] = SZ * (bx[32 + c0] + bh[32 + c0] + dbs * Wk[32 + c0]);
        crB[i] = SZ * (bx[32 + c1] + bh[32 + c1] + dbs * Wk[32 + c1]);
        chA[i] = SC * (bx[64 + c0] + dbs * Wk[64 + c0]);
        chB[i] = SC * (bx[64 + c1] + dbs * Wk[64 + c1]);
        cgA[i] = SC * bh[64 + c0];
        cgB[i] = SC * bh[64 + c1];
        dwA[i] = dw[c0];
        dwB[i] = dw[c1];
    }

    // ---- initial state (lane-local, permuted layout) ----
    float hc[8];
#pragma unroll
    for (int i = 0; i < 4; ++i) {
        hc[i]     = init_h[(size_t)(b0 + ln) * H_DIM + quad * 8 + i];
        hc[i + 4] = init_h[(size_t)(b0 + ln) * H_DIM + quad * 8 + 4 + i];
    }
    S8 hB;                                     // B-frag: k=q*8+j natural order
    hB.u[0] = pk_bf16(hc[1], hc[0]);
    hB.u[1] = pk_bf16(hc[3], hc[2]);
    hB.u[2] = pk_bf16(hc[5], hc[4]);
    hB.u[3] = pk_bf16(hc[7], hc[6]);

    // ---- step-0 delta: init_in - (h_init.dw + db)  (prologue, off-chain) ----
    float pv;
    {
        float d = fmaf(hc[0], dwA[0], hc[1] * dwA[1])
                + fmaf(hc[2], dwA[2], hc[3] * dwA[3]);
        d += fmaf(hc[4], dwB[0], hc[5] * dwB[1])
           + fmaf(hc[6], dwB[2], hc[7] * dwB[3]);
        d += SWZ16(d);
        d += __int_as_float(BPERM(bpa, __float_as_int(d)));
        pv = init_in[b0 + ln] - (d + dbs);     // injected at step 0 only
    }
    // Mask: only quad2's u[0] (K slots 16/17 = w0 rows) must be controlled in
    // the steady-state loop; all other "extra" B slots hit ZERO A-weights.
    const unsigned u0m = (quad == 2) ? 0u : 0xFFFFFFFFu;

    // ---- feat prefetch, depth 2 ----
    const float* fqb = feat + (size_t)(b0 + ln) * (T_STEPS * F_DIM) + (quad & 1) * 8;
    f32x4 pa0 = *(const f32x4*)(fqb);
    f32x4 pb0 = *(const f32x4*)(fqb + 4);
    f32x4 pa1 = *(const f32x4*)(fqb + F_DIM);
    f32x4 pb1 = *(const f32x4*)(fqb + F_DIM + 4);

    // ---- shared step body: MFMAs + stage-wise gates + repack + partial ----
#define STEP_CORE(T_, XA_) do {                                                \
        f32x4 aZA = czA, aRA = crA, aHA = chA, aGA = cgA;                      \
        f32x4 aZB = czB, aRB = crB, aHB = chB, aGB = cgB;                      \
        aZA = MFMA(WzA.s, XA_.s, aZA);  aZB = MFMA(WzB.s, XA_.s, aZB);         \
        aRA = MFMA(WrA.s, XA_.s, aRA);  aRB = MFMA(WrB.s, XA_.s, aRB);         \
        aHA = MFMA(WhA.s, XA_.s, aHA);  aHB = MFMA(WhB.s, XA_.s, aHB);         \
        aZA = MFMA(RzA.s, hB.s, aZA);   aZB = MFMA(RzB.s, hB.s, aZB);          \
        aRA = MFMA(RrA.s, hB.s, aRA);   aRB = MFMA(RrB.s, hB.s, aRB);          \
        aHA = MFMA(DwhA.s, hB.s, aHA);  aHB = MFMA(DwhB.s, hB.s, aHB);         \
        aGA = MFMA(RhA.s, hB.s, aGA);   aGB = MFMA(RhB.s, hB.s, aGB);          \
        float az[8], ar[8], ah[8], ag[8];                                      \
        _Pragma("unroll")                                                      \
        for (int i = 0; i < 4; ++i) {                                          \
            az[i] = aZA[i]; az[i + 4] = aZB[i];                                \
            ar[i] = aRA[i]; ar[i + 4] = aRB[i];                                \
            ah[i] = aHA[i]; ah[i + 4] = aHB[i];                                \
            ag[i] = aGA[i]; ag[i + 4] = aGB[i];                                \
        }                                                                      \
        float Ez[8], tr[8], rr[8], vv[8], Dv[8], num[8], den[8], rd[8];        \
        _Pragma("unroll")                                                      \
        for (int e = 0; e < 8; ++e) Ez[e] = ex2(az[e]);                        \
        _Pragma("unroll")                                                      \
        for (int e = 0; e < 8; ++e) tr[e] = ex2(ar[e]);                        \
        _Pragma("unroll")                                                      \
        for (int e = 0; e < 8; ++e) rr[e] = rcpf(1.0f + tr[e]);                \
        _Pragma("unroll")                                                      \
        for (int e = 0; e < 8; ++e) vv[e] = fmaf(rr[e], ag[e], ah[e]);         \
        _Pragma("unroll")                                                      \
        for (int e = 0; e < 8; ++e) Dv[e] = 1.0f + ex2(vv[e]);                 \
        _Pragma("unroll")                                                      \
        for (int e = 0; e < 8; ++e) num[e] = fmaf(hc[e], Dv[e],                \
                                                  (Dv[e] - 2.0f) * Ez[e]);     \
        _Pragma("unroll")                                                      \
        for (int e = 0; e < 8; ++e) den[e] = fmaf(Dv[e], Ez[e], Dv[e]);        \
        _Pragma("unroll")                                                      \
        for (int e = 0; e < 8; ++e) rd[e] = rcpf(den[e]);                      \
        _Pragma("unroll")                                                      \
        for (int e = 0; e < 8; ++e) hc[e] = num[e] * rd[e];                    \
        hB.u[0] = pk_bf16(hc[1], hc[0]);                                       \
        hB.u[1] = pk_bf16(hc[3], hc[2]);                                       \
        hB.u[2] = pk_bf16(hc[5], hc[4]);                                       \
        hB.u[3] = pk_bf16(hc[7], hc[6]);                                       \
        /* per-lane dense partial -> LDS; reduced in EPILOGUE (no wait) */     \
        float s = fmaf(hc[0], dwA[0], hc[1] * dwA[1])                          \
                + fmaf(hc[2], dwA[2], hc[3] * dwA[3]);                         \
        s += fmaf(hc[4], dwB[0], hc[5] * dwB[1])                               \
           + fmaf(hc[6], dwB[2], hc[7] * dwB[3]);                              \
        obuf[(T_) * 64 + lane] = s;                                            \
    } while (0)

#define PACK_XA(XA_, PA_, PB_) do {                                            \
        XA_.u[0] = pk_bf16(PA_[1], PA_[0]);                                    \
        XA_.u[1] = pk_bf16(PA_[3], PA_[2]);                                    \
        XA_.u[2] = pk_bf16(PB_[1], PB_[0]);                                    \
        XA_.u[3] = pk_bf16(PB_[3], PB_[2]);                                    \
    } while (0)

#define PREF(T_, PA_, PB_) do {                                                \
        const int t2 = ((T_) + 2 < T_STEPS) ? (T_) + 2 : T_STEPS - 1;          \
        PA_ = *(const f32x4*)(fqb + t2 * F_DIM);                               \
        PB_ = *(const f32x4*)(fqb + t2 * F_DIM + 4);                           \
    } while (0)

    // ---- step 0 (peeled: delta injection into K slots 16/17) ----
    {
        S8 xa;
        PACK_XA(xa, pa0, pb0);
        const float ph = __uint_as_float((__float_as_uint(pv) + 0x8000u) & 0xFFFF0000u);
        const unsigned dpk = pk_bf16(pv - ph, ph);
        xa.u[0] = (quad == 2) ? dpk : xa.u[0];
        PREF(0, pa0, pb0);
        STEP_CORE(0, xa);
    }
    // ---- steps 1..47 (lean: quad2 u[0] zeroed via precomputed mask) ----
    for (int t = 1; t < 47; t += 2) {
        {
            S8 xa;
            PACK_XA(xa, pa1, pb1);
            xa.u[0] &= u0m;
            PREF(t, pa1, pb1);
            STEP_CORE(t, xa);
        }
        {
            S8 xa;
            PACK_XA(xa, pa0, pb0);
            xa.u[0] &= u0m;
            PREF(t + 1, pa0, pb0);
            STEP_CORE(t + 1, xa);
        }
    }
    {
        S8 xa;
        PACK_XA(xa, pa1, pb1);
        xa.u[0] &= u0m;
        STEP_CORE(47, xa);
    }
#undef STEP_CORE
#undef PACK_XA
#undef PREF

    // ---- epilogue: reduce quad partials + store (single wave, off-chain) ----
    __builtin_amdgcn_s_waitcnt(0xC07F);            // drain obuf ds_writes
    {
        const int row = lane >> 2;                 // 0..15
        const int tb  = (lane & 3) * 12;           // 0,12,24,36
        float* orow = out + (size_t)(b0 + row) * T_STEPS + tb;
#pragma unroll
        for (int k = 0; k < 3; ++k) {
            f32x4 v;
#pragma unroll
            for (int e = 0; e < 4; ++e) {
                const int t = tb + k * 4 + e;
                const float p0 = obuf[t * 64 + row];           // quad 0
                const float p1 = obuf[t * 64 + 16 + row];      // quad 1
                const float p2 = obuf[t * 64 + 32 + row];      // quad 2
                const float p3 = obuf[t * 64 + 48 + row];      // quad 3
                // pairwise to bit-match old swz16(+q^1) then bperm(+q^2) tree
                v[e] = ((p0 + p1) + (p2 + p3)) + dbs;
            }
            *(f32x4*)(orow + k * 4) = v;
        }
    }
}

extern "C" void kernel_launch(void* const* d_in, const int* in_sizes, int n_in,
                              void* d_out, int out_size, void* d_ws, size_t ws_size,
                              hipStream_t stream) {
    const float* feat    = (const float*)d_in[0];
    const float* init_in = (const float*)d_in[1];
    const float* init_h  = (const float*)d_in[2];
    const float* Wk      = (const float*)d_in[3];
    const float* Rk      = (const float*)d_in[4];
    const float* bx      = (const float*)d_in[5];
    const float* bh      = (const float*)d_in[6];
    const float* dw      = (const float*)d_in[7];
    const float* db      = (const float*)d_in[8];
    float* out           = (float*)d_out;

    const int B = in_sizes[2] / H_DIM;      // 32768
    dim3 grid((unsigned)(B / 16));          // one 1-wave block per 16 batch rows
    dim3 block(64);
    hipLaunchKernelGGL(gru_mfma15, grid, block, 0, stream,
                       feat, init_in, init_h, Wk, Rk, bx, bh, dw, db, out);
}